// Round 22
// baseline (34.002 us; speedup 1.0000x reference)
//
#include <hip/hip_runtime.h>
#include <math.h>

constexpr int B = 256, STEP = 32, DF = 256, DZ = 64;
constexpr int TI = 8;                    // i-tile per k_z block
#define LOG_2PI 1.837877066409345f
#define LOG_C   16.36495572888985f       // log(256 * 50000)

__device__ __forceinline__ float warpReduceSum64(float v) {
    for (int o = 32; o > 0; o >>= 1) v += __shfl_down(v, o, 64);
    return v;
}

// 256-thread block reduction; lds4 = float[4]; result valid in ALL threads.
__device__ __forceinline__ float blockReduceSum256(float v, float* lds4) {
    int wid = threadIdx.x >> 6, lane = threadIdx.x & 63;
    v = warpReduceSum64(v);
    if (lane == 0) lds4[wid] = v;
    __syncthreads();
    float r = lds4[0] + lds4[1] + lds4[2] + lds4[3];
    __syncthreads();
    return r;
}

// pack e (lo) and me (hi) as bf16 with round-to-nearest-even
__device__ __forceinline__ unsigned pack_bf2(float e, float me) {
    unsigned eb = __float_as_uint(e);
    eb = (eb + 0x7fffu + ((eb >> 16) & 1u)) >> 16;
    unsigned mb = __float_as_uint(me);
    mb = (mb + 0x7fffu + ((mb >> 16) & 1u)) >> 16;
    return (mb << 16) | eb;
}

// K1: f-transpose (16 blocks): 64x64 tiles -> PACKED efb4 (64 chunks x 256 j), wcf_part.
__global__ __launch_bounds__(256) void k_pre_f(
        const float* __restrict__ fm, const float* __restrict__ fl,
        uint4* __restrict__ efb4, float* __restrict__ wcf_part) {
    int t = threadIdx.x;
    int wv = t >> 6, ln = t & 63;
    __shared__ float te[64][65], tme[64][65];
    int fb = blockIdx.x;                  // 0..15
    int j0 = (fb & 3) * 64, d0 = (fb >> 2) * 64, dq = fb >> 2;
    float red[16];
#pragma unroll 4
    for (int it = 0; it < 16; ++it) {
        int jr = it * 4 + wv, jg = j0 + jr;
        size_t src = (size_t)jg * DF + d0 + ln;   // 256B coalesced per wave
        float lv = fl[src], m = fm[src];
        float e = __expf(-lv);
        te[ln][jr] = e;
        tme[ln][jr] = m * e;
        red[it] = 2.0f * lv;
    }
#pragma unroll
    for (int o = 32; o > 0; o >>= 1)
#pragma unroll
        for (int k = 0; k < 16; ++k) red[k] += __shfl_xor(red[k], o, 64);
    if (ln == 0) {
#pragma unroll
        for (int k = 0; k < 16; ++k)
            wcf_part[dq * B + j0 + k * 4 + wv] = red[k];
    }
    __syncthreads();
#pragma unroll
    for (int it = 0; it < 4; ++it) {
        int r = it * 4 + wv;             // local chunk 0..15
        int gr = (d0 >> 2) + r;          // global chunk 0..63
        uint4 pv;
        pv.x = pack_bf2(te[4 * r + 0][ln], tme[4 * r + 0][ln]);
        pv.y = pack_bf2(te[4 * r + 1][ln], tme[4 * r + 1][ln]);
        pv.z = pack_bf2(te[4 * r + 2][ln], tme[4 * r + 2][ln]);
        pv.w = pack_bf2(te[4 * r + 3][ln], tme[4 * r + 3][ln]);
        efb4[(size_t)gr * B + j0 + ln] = pv;
    }
}

// K2: fused {z-transpose -> packed bf16 panel (blocks 0..127)} ||
//           {k_f: 4 i's per block, packed panel (blocks 128..191)}. Grid 192.
__global__ __launch_bounds__(256) void k2(
        const float* __restrict__ zm, const float* __restrict__ zl,
        const float* __restrict__ fs, const uint4* __restrict__ efb4,
        const float* __restrict__ wcf_part,
        uint4* __restrict__ ezb4, float* __restrict__ wc,
        float* __restrict__ sum_f, float* __restrict__ hneg_f) {
    int t = threadIdx.x;
    if (blockIdx.x < 128) {
        // ---- z transpose -> packed (e,me) bf16 pairs ----
        int wv = t >> 6, ln = t & 63;
        __shared__ float te[64][65], tme[64][65];
        int s = blockIdx.x >> 2, j0 = (blockIdx.x & 3) * 64;
        float red[16];
#pragma unroll 4
        for (int it = 0; it < 16; ++it) {
            int jr = it * 4 + wv, jg = j0 + jr;
            size_t src = ((size_t)jg * STEP + s) * DZ + ln;   // 256B coalesced
            float lv = zl[src], m = zm[src];
            float e = __expf(-lv);
            te[ln][jr] = e;
            tme[ln][jr] = m * e;
            red[it] = 2.0f * lv;
        }
#pragma unroll
        for (int o = 32; o > 0; o >>= 1)
#pragma unroll
            for (int k = 0; k < 16; ++k) red[k] += __shfl_xor(red[k], o, 64);
        if (ln == 0) {
#pragma unroll
            for (int k = 0; k < 16; ++k)
                wc[s * B + j0 + k * 4 + wv] = red[k] + (float)DZ * LOG_2PI;
        }
        __syncthreads();
        uint4* ez = ezb4 + (size_t)s * 16 * B;
#pragma unroll
        for (int it = 0; it < 4; ++it) {
            int r = it * 4 + wv;   // chunk 0..15 (dims 4r..4r+3)
            uint4 pv;
            pv.x = pack_bf2(te[4 * r + 0][ln], tme[4 * r + 0][ln]);
            pv.y = pack_bf2(te[4 * r + 1][ln], tme[4 * r + 1][ln]);
            pv.z = pack_bf2(te[4 * r + 2][ln], tme[4 * r + 2][ln]);
            pv.w = pack_bf2(te[4 * r + 3][ln], tme[4 * r + 3][ln]);
            ez[(size_t)r * B + j0 + ln] = pv;          // 1KB coalesced per wave
        }
    } else {
        // ---- k_f: 4 i's per block, thread j does full 256-d dots, packed panel ----
        int ib = (blockIdx.x - 128) * 4;
        int j = t;
        __shared__ float red2[4][4];
        const float4* f0 = reinterpret_cast<const float4*>(fs + (size_t)(ib + 0) * DF);
        const float4* f1 = reinterpret_cast<const float4*>(fs + (size_t)(ib + 1) * DF);
        const float4* f2 = reinterpret_cast<const float4*>(fs + (size_t)(ib + 2) * DF);
        const float4* f3 = reinterpret_cast<const float4*>(fs + (size_t)(ib + 3) * DF);
        const uint4* pp = efb4 + j;
        float a0 = 0.0f, a1 = 0.0f, a2 = 0.0f, a3 = 0.0f;
        uint4 A = pp[0];
        uint4 Bv = pp[(size_t)B];
        uint4 C = pp[(size_t)2 * B];
#pragma unroll
        for (int c = 0; c < 64; ++c) {
            uint4 N = make_uint4(0u, 0u, 0u, 0u);
            if (c + 3 < 64) N = pp[(size_t)(c + 3) * B];
            float e0 = __uint_as_float(A.x << 16), me0 = __uint_as_float(A.x & 0xffff0000u);
            float e1 = __uint_as_float(A.y << 16), me1 = __uint_as_float(A.y & 0xffff0000u);
            float e2 = __uint_as_float(A.z << 16), me2 = __uint_as_float(A.z & 0xffff0000u);
            float e3 = __uint_as_float(A.w << 16), me3 = __uint_as_float(A.w & 0xffff0000u);
            float4 s0 = f0[c], s1 = f1[c], s2 = f2[c], s3 = f3[c];
            float u0, u1, u2, u3;
            u0 = fmaf(s0.x, e0, -me0); u1 = fmaf(s0.y, e1, -me1);
            u2 = fmaf(s0.z, e2, -me2); u3 = fmaf(s0.w, e3, -me3);
            a0 = fmaf(u0, u0, a0); a0 = fmaf(u1, u1, a0);
            a0 = fmaf(u2, u2, a0); a0 = fmaf(u3, u3, a0);
            u0 = fmaf(s1.x, e0, -me0); u1 = fmaf(s1.y, e1, -me1);
            u2 = fmaf(s1.z, e2, -me2); u3 = fmaf(s1.w, e3, -me3);
            a1 = fmaf(u0, u0, a1); a1 = fmaf(u1, u1, a1);
            a1 = fmaf(u2, u2, a1); a1 = fmaf(u3, u3, a1);
            u0 = fmaf(s2.x, e0, -me0); u1 = fmaf(s2.y, e1, -me1);
            u2 = fmaf(s2.z, e2, -me2); u3 = fmaf(s2.w, e3, -me3);
            a2 = fmaf(u0, u0, a2); a2 = fmaf(u1, u1, a2);
            a2 = fmaf(u2, u2, a2); a2 = fmaf(u3, u3, a2);
            u0 = fmaf(s3.x, e0, -me0); u1 = fmaf(s3.y, e1, -me1);
            u2 = fmaf(s3.z, e2, -me2); u3 = fmaf(s3.w, e3, -me3);
            a3 = fmaf(u0, u0, a3); a3 = fmaf(u1, u1, a3);
            a3 = fmaf(u2, u2, a3); a3 = fmaf(u3, u3, a3);
            A = Bv; Bv = C; C = N;
        }
        float wcf = wcf_part[j] + wcf_part[B + j] + wcf_part[2 * B + j]
                  + wcf_part[3 * B + j] + (float)DF * LOG_2PI;
        float v0 = -0.5f * (a0 + wcf);
        float v1 = -0.5f * (a1 + wcf);
        float v2 = -0.5f * (a2 + wcf);
        float v3 = -0.5f * (a3 + wcf);
        sum_f[(size_t)(ib + 0) * B + j] = v0;
        sum_f[(size_t)(ib + 1) * B + j] = v1;
        sum_f[(size_t)(ib + 2) * B + j] = v2;
        sum_f[(size_t)(ib + 3) * B + j] = v3;
        // 4-chain batched 256-thread LSE
        int wid = j >> 6, lane = j & 63;
        float m0 = v0, m1 = v1, m2 = v2, m3 = v3;
#pragma unroll
        for (int o = 32; o > 0; o >>= 1) {
            m0 = fmaxf(m0, __shfl_xor(m0, o, 64));
            m1 = fmaxf(m1, __shfl_xor(m1, o, 64));
            m2 = fmaxf(m2, __shfl_xor(m2, o, 64));
            m3 = fmaxf(m3, __shfl_xor(m3, o, 64));
        }
        if (lane == 0) { red2[0][wid] = m0; red2[1][wid] = m1;
                         red2[2][wid] = m2; red2[3][wid] = m3; }
        __syncthreads();
        m0 = fmaxf(fmaxf(red2[0][0], red2[0][1]), fmaxf(red2[0][2], red2[0][3]));
        m1 = fmaxf(fmaxf(red2[1][0], red2[1][1]), fmaxf(red2[1][2], red2[1][3]));
        m2 = fmaxf(fmaxf(red2[2][0], red2[2][1]), fmaxf(red2[2][2], red2[2][3]));
        m3 = fmaxf(fmaxf(red2[3][0], red2[3][1]), fmaxf(red2[3][2], red2[3][3]));
        __syncthreads();
        float p0 = __expf(v0 - m0), p1 = __expf(v1 - m1);
        float p2 = __expf(v2 - m2), p3 = __expf(v3 - m3);
#pragma unroll
        for (int o = 32; o > 0; o >>= 1) {
            p0 += __shfl_xor(p0, o, 64);
            p1 += __shfl_xor(p1, o, 64);
            p2 += __shfl_xor(p2, o, 64);
            p3 += __shfl_xor(p3, o, 64);
        }
        if (lane == 0) { red2[0][wid] = p0; red2[1][wid] = p1;
                         red2[2][wid] = p2; red2[3][wid] = p3; }
        __syncthreads();
        if (j == 0) {
#pragma unroll
            for (int q = 0; q < 4; ++q) {
                float sq = red2[q][0] + red2[q][1] + red2[q][2] + red2[q][3];
                float mq = (q == 0) ? m0 : (q == 1) ? m1 : (q == 2) ? m2 : m3;
                hneg_f[ib + q] = fmaxf(-(mq + __logf(sq) - LOG_C), 0.0f);
            }
        }
    }
}

// K3 = k_z: 1024 blocks, TI=8, XCD-swizzled; packed bf16 panel; conflict-free vls perm.
__global__ __launch_bounds__(256, 8) void k_z(
        const uint4* __restrict__ ezb4, const float* __restrict__ wc,
        const float* __restrict__ zs,
        const float* __restrict__ sum_f,
        float* __restrict__ hneg_z, float* __restrict__ hneg_fz) {
    int b = blockIdx.x;
    int x = b & 7, r = b >> 3;
    int it = r & 31, g = r >> 5;
    int s = x + 8 * g;
    int j = threadIdx.x;
    int i0 = it * TI;
    __shared__ float4 zs_sh[TI][16];           // 2 KB
    __shared__ float vls[2 * TI][260];         // 16.6 KB

    if (j < TI * 16) {   // stage TI zs rows (each row 256B contiguous)
        int ii = j >> 4, c = j & 15;
        zs_sh[ii][c] = *reinterpret_cast<const float4*>(
            &zs[((size_t)(i0 + ii) * STEP + s) * DZ + c * 4]);
    }
    __syncthreads();

    float wcj = wc[s * B + j];
    float sf[TI];
#pragma unroll
    for (int i = 0; i < TI; ++i) sf[i] = sum_f[(size_t)(i0 + i) * B + j];

    const uint4* pv = ezb4 + (size_t)s * 16 * B + j;   // packed chunks, lane-coalesced
    float acc[TI];
#pragma unroll
    for (int i = 0; i < TI; ++i) acc[i] = 0.0f;

    // depth-2 software pipeline over the 16 packed chunks
    uint4 A = pv[0];
    uint4 Bv = pv[(size_t)B];
#pragma unroll
    for (int c = 0; c < 16; ++c) {
        uint4 N = make_uint4(0u, 0u, 0u, 0u);
        if (c + 2 < 16) N = pv[(size_t)(c + 2) * B];
        float e0 = __uint_as_float(A.x << 16), me0 = __uint_as_float(A.x & 0xffff0000u);
        float e1 = __uint_as_float(A.y << 16), me1 = __uint_as_float(A.y & 0xffff0000u);
        float e2 = __uint_as_float(A.z << 16), me2 = __uint_as_float(A.z & 0xffff0000u);
        float e3 = __uint_as_float(A.w << 16), me3 = __uint_as_float(A.w & 0xffff0000u);
#pragma unroll
        for (int i = 0; i < TI; ++i) {
            float4 sv = zs_sh[i][c];               // LDS broadcast (conflict-free)
            float t0 = fmaf(sv.x, e0, -me0);
            float t1 = fmaf(sv.y, e1, -me1);
            float t2 = fmaf(sv.z, e2, -me2);
            float t3 = fmaf(sv.w, e3, -me3);
            acc[i] = fmaf(t0, t0, acc[i]);
            acc[i] = fmaf(t1, t1, acc[i]);
            acc[i] = fmaf(t2, t2, acc[i]);
            acc[i] = fmaf(t3, t3, acc[i]);
        }
        A = Bv; Bv = N;
    }

    // ---- LSE via LDS transpose: thread j writes 16 chain values to column j ----
#pragma unroll
    for (int i = 0; i < TI; ++i) {
        float a = -0.5f * (acc[i] + wcj);
        vls[2 * i][j] = a;
        vls[2 * i + 1][j] = a + sf[i];
    }
    __syncthreads();

    // task k = j>>4 (16 threads, in-wave); thread e reads 16 j-values.
    // perm ((e>>1)+q)&3 -> colliding lanes {e,e+4,e+8,e+12} take distinct perms (2-way max).
    int k = j >> 4, e = j & 15;
    const float4* rowp = reinterpret_cast<const float4*>(&vls[k][0]);
    float4 q0 = rowp[e * 4 + (((e >> 1) + 0) & 3)];
    float4 q1 = rowp[e * 4 + (((e >> 1) + 1) & 3)];
    float4 q2 = rowp[e * 4 + (((e >> 1) + 2) & 3)];
    float4 q3 = rowp[e * 4 + (((e >> 1) + 3) & 3)];
    float m = fmaxf(fmaxf(fmaxf(q0.x, q0.y), fmaxf(q0.z, q0.w)),
                    fmaxf(fmaxf(q1.x, q1.y), fmaxf(q1.z, q1.w)));
    m = fmaxf(m, fmaxf(fmaxf(fmaxf(q2.x, q2.y), fmaxf(q2.z, q2.w)),
                       fmaxf(fmaxf(q3.x, q3.y), fmaxf(q3.z, q3.w))));
#pragma unroll
    for (int o = 1; o <= 8; o <<= 1) m = fmaxf(m, __shfl_xor(m, o, 64));
    float ssum = __expf(q0.x - m) + __expf(q0.y - m) + __expf(q0.z - m) + __expf(q0.w - m)
               + __expf(q1.x - m) + __expf(q1.y - m) + __expf(q1.z - m) + __expf(q1.w - m)
               + __expf(q2.x - m) + __expf(q2.y - m) + __expf(q2.z - m) + __expf(q2.w - m)
               + __expf(q3.x - m) + __expf(q3.y - m) + __expf(q3.z - m) + __expf(q3.w - m);
#pragma unroll
    for (int o = 1; o <= 8; o <<= 1) ssum += __shfl_xor(ssum, o, 64);
    if (e == 0) {
        float h = fmaxf(-(m + __logf(ssum) - LOG_C), 0.0f);
        int i = k >> 1;
        if (k & 1) hneg_fz[s * B + i0 + i] = h;
        else       hneg_z[s * B + i0 + i] = h;
    }
}

// K4 = k_final: 1 block, deterministic reduction -> scalar.
__global__ __launch_bounds__(256) void k_final(
        const float* __restrict__ hneg_f, const float* __restrict__ hneg_z,
        const float* __restrict__ hneg_fz, float* __restrict__ out) {
    __shared__ float lds4[4];
    int t = threadIdx.x;
    float sf = hneg_f[t];
    float szv = 0.0f, sfz = 0.0f;
#pragma unroll 8
    for (int k = 0; k < STEP; ++k) {       // fixed order per thread -> deterministic
        szv += hneg_z[k * B + t];
        sfz += hneg_fz[k * B + t];
    }
    float Hf  = blockReduceSum256(sf, lds4) * (1.0f / B);
    float Hz  = blockReduceSum256(szv, lds4) * (1.0f / (STEP * B));
    float Hfz = blockReduceSum256(sfz, lds4) * (1.0f / (STEP * B));
    if (t == 0) out[0] = Hf + Hz - Hfz;
}

extern "C" void kernel_launch(void* const* d_in, const int* in_sizes, int n_in,
                              void* d_out, int out_size, void* d_ws, size_t ws_size,
                              hipStream_t stream) {
    const float* f_mean   = (const float*)d_in[0];
    const float* f_logvar = (const float*)d_in[1];
    const float* f_sample = (const float*)d_in[2];
    const float* z_mean   = (const float*)d_in[3];
    const float* z_logvar = (const float*)d_in[4];
    const float* z_sample = (const float*)d_in[5];
    float* out = (float*)d_out;

    float* w = (float*)d_ws;
    float* sum_f    = w;  w += B * B;               // 65536
    float* hneg_f   = w;  w += B;                   // 256
    float* hneg_z   = w;  w += STEP * B;            // 8192
    float* hneg_fz  = w;  w += STEP * B;            // 8192
    uint4* ezb4     = (uint4*)w;  w += STEP * 16 * B * 4;    // 2 MB packed z panel
    float* wc       = w;  w += STEP * B;            // 8192
    uint4* efb4     = (uint4*)w;  w += 64 * B * 4;           // 256 KB packed f panel
    float* wcf_part = w;  w += 4 * B;               // 1024

    k_pre_f<<<dim3(16), dim3(256), 0, stream>>>(f_mean, f_logvar, efb4, wcf_part);
    k2<<<dim3(192), dim3(256), 0, stream>>>(z_mean, z_logvar, f_sample, efb4,
                                            wcf_part, ezb4, wc, sum_f, hneg_f);
    k_z<<<dim3((B / TI) * STEP), dim3(256), 0, stream>>>(ezb4, wc, z_sample,
                                                         sum_f, hneg_z, hneg_fz);
    k_final<<<dim3(1), dim3(256), 0, stream>>>(hneg_f, hneg_z, hneg_fz, out);
}

// Round 23
// 32.281 us; speedup vs baseline: 1.0533x; 1.0533x over previous
//
#include <hip/hip_runtime.h>
#include <math.h>

constexpr int B = 256, STEP = 32, DF = 256, DZ = 64;
constexpr int TI = 8;                    // i-tile per k_z block
#define LOG_2PI 1.837877066409345f
#define LOG_C   16.36495572888985f       // log(256 * 50000)

__device__ __forceinline__ float warpReduceSum64(float v) {
    for (int o = 32; o > 0; o >>= 1) v += __shfl_down(v, o, 64);
    return v;
}

// 256-thread block reduction; lds4 = float[4]; result valid in ALL threads.
__device__ __forceinline__ float blockReduceSum256(float v, float* lds4) {
    int wid = threadIdx.x >> 6, lane = threadIdx.x & 63;
    v = warpReduceSum64(v);
    if (lane == 0) lds4[wid] = v;
    __syncthreads();
    float r = lds4[0] + lds4[1] + lds4[2] + lds4[3];
    __syncthreads();
    return r;
}

// pack e (lo) and me (hi) as bf16 with round-to-nearest-even
__device__ __forceinline__ unsigned pack_bf2(float e, float me) {
    unsigned eb = __float_as_uint(e);
    eb = (eb + 0x7fffu + ((eb >> 16) & 1u)) >> 16;
    unsigned mb = __float_as_uint(me);
    mb = (mb + 0x7fffu + ((mb >> 16) & 1u)) >> 16;
    return (mb << 16) | eb;
}

// K1: f-transpose only (16 blocks): 64x64 tiles -> eft4 (r<64 e, r>=64 me), wcf_part.
__global__ __launch_bounds__(256) void k_pre_f(
        const float* __restrict__ fm, const float* __restrict__ fl,
        float4* __restrict__ eft4, float* __restrict__ wcf_part) {
    int t = threadIdx.x;
    int wv = t >> 6, ln = t & 63;
    __shared__ float te[64][65], tme[64][65];
    int fb = blockIdx.x;                  // 0..15
    int j0 = (fb & 3) * 64, d0 = (fb >> 2) * 64, dq = fb >> 2;
    float red[16];
#pragma unroll 4
    for (int it = 0; it < 16; ++it) {
        int jr = it * 4 + wv, jg = j0 + jr;
        size_t src = (size_t)jg * DF + d0 + ln;   // 256B coalesced per wave
        float lv = fl[src], m = fm[src];
        float e = __expf(-lv);
        te[ln][jr] = e;
        tme[ln][jr] = m * e;
        red[it] = 2.0f * lv;
    }
#pragma unroll
    for (int o = 32; o > 0; o >>= 1)
#pragma unroll
        for (int k = 0; k < 16; ++k) red[k] += __shfl_xor(red[k], o, 64);
    if (ln == 0) {
#pragma unroll
        for (int k = 0; k < 16; ++k)
            wcf_part[dq * B + j0 + k * 4 + wv] = red[k];
    }
    __syncthreads();
#pragma unroll
    for (int it = 0; it < 4; ++it) {
        int r = it * 4 + wv;             // local chunk 0..15
        int gr = (d0 >> 2) + r;          // global chunk 0..63
        float4 evv = make_float4(te[4 * r + 0][ln], te[4 * r + 1][ln],
                                 te[4 * r + 2][ln], te[4 * r + 3][ln]);
        float4 mvv = make_float4(tme[4 * r + 0][ln], tme[4 * r + 1][ln],
                                 tme[4 * r + 2][ln], tme[4 * r + 3][ln]);
        eft4[(size_t)gr * B + j0 + ln] = evv;
        eft4[(size_t)(64 + gr) * B + j0 + ln] = mvv;
    }
}

// K2: fused {z-transpose -> PACKED bf16 panel (blocks 0..127)} || {k_f (blocks 128..255)}.
__global__ __launch_bounds__(256) void k2(
        const float* __restrict__ zm, const float* __restrict__ zl,
        const float* __restrict__ fs, const float4* __restrict__ eft4,
        const float* __restrict__ wcf_part,
        uint4* __restrict__ ezb4, float* __restrict__ wc,
        float* __restrict__ sum_f, float* __restrict__ hneg_f) {
    int t = threadIdx.x;
    if (blockIdx.x < 128) {
        // ---- z transpose -> packed (e,me) bf16 pairs ----
        int wv = t >> 6, ln = t & 63;
        __shared__ float te[64][65], tme[64][65];
        int s = blockIdx.x >> 2, j0 = (blockIdx.x & 3) * 64;
        float red[16];
#pragma unroll 4
        for (int it = 0; it < 16; ++it) {
            int jr = it * 4 + wv, jg = j0 + jr;
            size_t src = ((size_t)jg * STEP + s) * DZ + ln;   // 256B coalesced
            float lv = zl[src], m = zm[src];
            float e = __expf(-lv);
            te[ln][jr] = e;
            tme[ln][jr] = m * e;
            red[it] = 2.0f * lv;
        }
#pragma unroll
        for (int o = 32; o > 0; o >>= 1)
#pragma unroll
            for (int k = 0; k < 16; ++k) red[k] += __shfl_xor(red[k], o, 64);
        if (ln == 0) {
#pragma unroll
            for (int k = 0; k < 16; ++k)
                wc[s * B + j0 + k * 4 + wv] = red[k] + (float)DZ * LOG_2PI;
        }
        __syncthreads();
        uint4* ez = ezb4 + (size_t)s * 16 * B;
#pragma unroll
        for (int it = 0; it < 4; ++it) {
            int r = it * 4 + wv;   // chunk 0..15 (dims 4r..4r+3)
            uint4 pv;
            pv.x = pack_bf2(te[4 * r + 0][ln], tme[4 * r + 0][ln]);
            pv.y = pack_bf2(te[4 * r + 1][ln], tme[4 * r + 1][ln]);
            pv.z = pack_bf2(te[4 * r + 2][ln], tme[4 * r + 2][ln]);
            pv.w = pack_bf2(te[4 * r + 3][ln], tme[4 * r + 3][ln]);
            ez[(size_t)r * B + j0 + ln] = pv;          // 1KB coalesced per wave
        }
    } else {
        // ---- k_f: 2 i's per block, thread j does full 256-d dots (fp32 path) ----
        int ib = (blockIdx.x - 128) * 2;
        int j = t;
        __shared__ float red2[2][4];
        const float4* f0 = reinterpret_cast<const float4*>(fs + (size_t)(ib + 0) * DF);
        const float4* f1 = reinterpret_cast<const float4*>(fs + (size_t)(ib + 1) * DF);
        const float4* ep = eft4 + j;
        const float4* mp = eft4 + (size_t)64 * B + j;
        float a0 = 0.0f, a1 = 0.0f;
        float4 eA = ep[0], mA = mp[0];
        float4 eB = ep[(size_t)B], mB = mp[(size_t)B];
        float4 eC = ep[(size_t)2 * B], mC = mp[(size_t)2 * B];
#pragma unroll
        for (int c = 0; c < 64; ++c) {
            float4 eN = make_float4(0.f, 0.f, 0.f, 0.f), mN = eN;
            if (c + 3 < 64) { eN = ep[(size_t)(c + 3) * B]; mN = mp[(size_t)(c + 3) * B]; }
            float4 s0 = f0[c], s1 = f1[c];
            float u0 = fmaf(s0.x, eA.x, -mA.x);
            float u1 = fmaf(s0.y, eA.y, -mA.y);
            float u2 = fmaf(s0.z, eA.z, -mA.z);
            float u3 = fmaf(s0.w, eA.w, -mA.w);
            a0 = fmaf(u0, u0, a0); a0 = fmaf(u1, u1, a0);
            a0 = fmaf(u2, u2, a0); a0 = fmaf(u3, u3, a0);
            float w0 = fmaf(s1.x, eA.x, -mA.x);
            float w1 = fmaf(s1.y, eA.y, -mA.y);
            float w2 = fmaf(s1.z, eA.z, -mA.z);
            float w3 = fmaf(s1.w, eA.w, -mA.w);
            a1 = fmaf(w0, w0, a1); a1 = fmaf(w1, w1, a1);
            a1 = fmaf(w2, w2, a1); a1 = fmaf(w3, w3, a1);
            eA = eB; mA = mB; eB = eC; mB = mC; eC = eN; mC = mN;
        }
        float wcf = wcf_part[j] + wcf_part[B + j] + wcf_part[2 * B + j]
                  + wcf_part[3 * B + j] + (float)DF * LOG_2PI;
        float v0 = -0.5f * (a0 + wcf);
        float v1 = -0.5f * (a1 + wcf);
        sum_f[(size_t)(ib + 0) * B + j] = v0;
        sum_f[(size_t)(ib + 1) * B + j] = v1;
        // 2-chain 256-thread LSE
        int wid = j >> 6, lane = j & 63;
        float m0 = v0, m1 = v1;
#pragma unroll
        for (int o = 32; o > 0; o >>= 1) {
            m0 = fmaxf(m0, __shfl_xor(m0, o, 64));
            m1 = fmaxf(m1, __shfl_xor(m1, o, 64));
        }
        if (lane == 0) { red2[0][wid] = m0; red2[1][wid] = m1; }
        __syncthreads();
        m0 = fmaxf(fmaxf(red2[0][0], red2[0][1]), fmaxf(red2[0][2], red2[0][3]));
        m1 = fmaxf(fmaxf(red2[1][0], red2[1][1]), fmaxf(red2[1][2], red2[1][3]));
        __syncthreads();
        float p0 = __expf(v0 - m0), p1 = __expf(v1 - m1);
#pragma unroll
        for (int o = 32; o > 0; o >>= 1) {
            p0 += __shfl_xor(p0, o, 64);
            p1 += __shfl_xor(p1, o, 64);
        }
        if (lane == 0) { red2[0][wid] = p0; red2[1][wid] = p1; }
        __syncthreads();
        if (j == 0) {
            float s0 = red2[0][0] + red2[0][1] + red2[0][2] + red2[0][3];
            float s1 = red2[1][0] + red2[1][1] + red2[1][2] + red2[1][3];
            hneg_f[ib + 0] = fmaxf(-(m0 + __logf(s0) - LOG_C), 0.0f);
            hneg_f[ib + 1] = fmaxf(-(m1 + __logf(s1) - LOG_C), 0.0f);
        }
    }
}

// K3 = k_z: 1024 blocks, TI=8, XCD-swizzled; packed bf16 panel; 8 blocks/CU;
// conflict-free vls perm ((e>>1)+q)&3.
__global__ __launch_bounds__(256, 8) void k_z(
        const uint4* __restrict__ ezb4, const float* __restrict__ wc,
        const float* __restrict__ zs,
        const float* __restrict__ sum_f,
        float* __restrict__ hneg_z, float* __restrict__ hneg_fz) {
    int b = blockIdx.x;
    int x = b & 7, r = b >> 3;
    int it = r & 31, g = r >> 5;
    int s = x + 8 * g;
    int j = threadIdx.x;
    int i0 = it * TI;
    __shared__ float4 zs_sh[TI][16];           // 2 KB
    __shared__ float vls[2 * TI][260];         // 16.6 KB

    if (j < TI * 16) {   // stage TI zs rows (each row 256B contiguous)
        int ii = j >> 4, c = j & 15;
        zs_sh[ii][c] = *reinterpret_cast<const float4*>(
            &zs[((size_t)(i0 + ii) * STEP + s) * DZ + c * 4]);
    }
    __syncthreads();

    float wcj = wc[s * B + j];
    float sf[TI];
#pragma unroll
    for (int i = 0; i < TI; ++i) sf[i] = sum_f[(size_t)(i0 + i) * B + j];

    const uint4* pv = ezb4 + (size_t)s * 16 * B + j;   // packed chunks, lane-coalesced
    float acc[TI];
#pragma unroll
    for (int i = 0; i < TI; ++i) acc[i] = 0.0f;

    // depth-2 software pipeline over the 16 packed chunks
    uint4 A = pv[0];
    uint4 Bv = pv[(size_t)B];
#pragma unroll
    for (int c = 0; c < 16; ++c) {
        uint4 N = make_uint4(0u, 0u, 0u, 0u);
        if (c + 2 < 16) N = pv[(size_t)(c + 2) * B];
        float e0 = __uint_as_float(A.x << 16), me0 = __uint_as_float(A.x & 0xffff0000u);
        float e1 = __uint_as_float(A.y << 16), me1 = __uint_as_float(A.y & 0xffff0000u);
        float e2 = __uint_as_float(A.z << 16), me2 = __uint_as_float(A.z & 0xffff0000u);
        float e3 = __uint_as_float(A.w << 16), me3 = __uint_as_float(A.w & 0xffff0000u);
#pragma unroll
        for (int i = 0; i < TI; ++i) {
            float4 sv = zs_sh[i][c];               // LDS broadcast (conflict-free)
            float t0 = fmaf(sv.x, e0, -me0);
            float t1 = fmaf(sv.y, e1, -me1);
            float t2 = fmaf(sv.z, e2, -me2);
            float t3 = fmaf(sv.w, e3, -me3);
            acc[i] = fmaf(t0, t0, acc[i]);
            acc[i] = fmaf(t1, t1, acc[i]);
            acc[i] = fmaf(t2, t2, acc[i]);
            acc[i] = fmaf(t3, t3, acc[i]);
        }
        A = Bv; Bv = N;
    }

    // ---- LSE via LDS transpose: thread j writes 16 chain values to column j ----
#pragma unroll
    for (int i = 0; i < TI; ++i) {
        float a = -0.5f * (acc[i] + wcj);
        vls[2 * i][j] = a;
        vls[2 * i + 1][j] = a + sf[i];
    }
    __syncthreads();

    // task k = j>>4 (16 threads, in-wave); thread e reads 16 j-values.
    // perm ((e>>1)+q)&3: lanes {e,e+4,e+8,e+12} (same base bank) take distinct perms.
    int k = j >> 4, e = j & 15;
    const float4* rowp = reinterpret_cast<const float4*>(&vls[k][0]);
    float4 q0 = rowp[e * 4 + (((e >> 1) + 0) & 3)];
    float4 q1 = rowp[e * 4 + (((e >> 1) + 1) & 3)];
    float4 q2 = rowp[e * 4 + (((e >> 1) + 2) & 3)];
    float4 q3 = rowp[e * 4 + (((e >> 1) + 3) & 3)];
    float m = fmaxf(fmaxf(fmaxf(q0.x, q0.y), fmaxf(q0.z, q0.w)),
                    fmaxf(fmaxf(q1.x, q1.y), fmaxf(q1.z, q1.w)));
    m = fmaxf(m, fmaxf(fmaxf(fmaxf(q2.x, q2.y), fmaxf(q2.z, q2.w)),
                       fmaxf(fmaxf(q3.x, q3.y), fmaxf(q3.z, q3.w))));
#pragma unroll
    for (int o = 1; o <= 8; o <<= 1) m = fmaxf(m, __shfl_xor(m, o, 64));
    float ssum = __expf(q0.x - m) + __expf(q0.y - m) + __expf(q0.z - m) + __expf(q0.w - m)
               + __expf(q1.x - m) + __expf(q1.y - m) + __expf(q1.z - m) + __expf(q1.w - m)
               + __expf(q2.x - m) + __expf(q2.y - m) + __expf(q2.z - m) + __expf(q2.w - m)
               + __expf(q3.x - m) + __expf(q3.y - m) + __expf(q3.z - m) + __expf(q3.w - m);
#pragma unroll
    for (int o = 1; o <= 8; o <<= 1) ssum += __shfl_xor(ssum, o, 64);
    if (e == 0) {
        float h = fmaxf(-(m + __logf(ssum) - LOG_C), 0.0f);
        int i = k >> 1;
        if (k & 1) hneg_fz[s * B + i0 + i] = h;
        else       hneg_z[s * B + i0 + i] = h;
    }
}

// K4 = k_final: 1 block, deterministic reduction -> scalar.
__global__ __launch_bounds__(256) void k_final(
        const float* __restrict__ hneg_f, const float* __restrict__ hneg_z,
        const float* __restrict__ hneg_fz, float* __restrict__ out) {
    __shared__ float lds4[4];
    int t = threadIdx.x;
    float sf = hneg_f[t];
    float szv = 0.0f, sfz = 0.0f;
#pragma unroll 8
    for (int k = 0; k < STEP; ++k) {       // fixed order per thread -> deterministic
        szv += hneg_z[k * B + t];
        sfz += hneg_fz[k * B + t];
    }
    float Hf  = blockReduceSum256(sf, lds4) * (1.0f / B);
    float Hz  = blockReduceSum256(szv, lds4) * (1.0f / (STEP * B));
    float Hfz = blockReduceSum256(sfz, lds4) * (1.0f / (STEP * B));
    if (t == 0) out[0] = Hf + Hz - Hfz;
}

extern "C" void kernel_launch(void* const* d_in, const int* in_sizes, int n_in,
                              void* d_out, int out_size, void* d_ws, size_t ws_size,
                              hipStream_t stream) {
    const float* f_mean   = (const float*)d_in[0];
    const float* f_logvar = (const float*)d_in[1];
    const float* f_sample = (const float*)d_in[2];
    const float* z_mean   = (const float*)d_in[3];
    const float* z_logvar = (const float*)d_in[4];
    const float* z_sample = (const float*)d_in[5];
    float* out = (float*)d_out;

    float* w = (float*)d_ws;
    float* sum_f    = w;  w += B * B;               // 65536
    float* hneg_f   = w;  w += B;                   // 256
    float* hneg_z   = w;  w += STEP * B;            // 8192
    float* hneg_fz  = w;  w += STEP * B;            // 8192
    uint4* ezb4     = (uint4*)w;  w += STEP * 16 * B * 4;    // 2 MB packed panel
    float* wc       = w;  w += STEP * B;            // 8192
    float4* eft4    = (float4*)w;  w += 128 * B * 4;         // 512 KB, [128][256] float4
    float* wcf_part = w;  w += 4 * B;               // 1024

    k_pre_f<<<dim3(16), dim3(256), 0, stream>>>(f_mean, f_logvar, eft4, wcf_part);
    k2<<<dim3(256), dim3(256), 0, stream>>>(z_mean, z_logvar, f_sample, eft4,
                                            wcf_part, ezb4, wc, sum_f, hneg_f);
    k_z<<<dim3((B / TI) * STEP), dim3(256), 0, stream>>>(ezb4, wc, z_sample,
                                                         sum_f, hneg_z, hneg_fz);
    k_final<<<dim3(1), dim3(256), 0, stream>>>(hneg_f, hneg_z, hneg_fz, out);
}